// Round 8
// baseline (2127.923 us; speedup 1.0000x reference)
//
#include <hip/hip_runtime.h>
#include <stdint.h>

#define T_ 512
#define B_ 64
#define H_ 512
#define L_ 2
#define TBH (T_*B_*H_)   // 16777216
#define BH  (B_*H_)      // 32768
#define NC  16           // time chunks
#define CS  32           // steps per chunk
#define CROWS (CS*B_)    // 2048 rows per chunk
#define CSZ ((size_t)CROWS*H_)        // floats per chunk slot (4 MiB)
#define BAR_BYTE_OFF ((size_t)4*CSZ*4)  // barrier word after the 4-slot ring (16 MiB)
#define NWG 192
#define NSTAGE (NC+3)    // s = -1 .. NC+1

typedef float    f32x4 __attribute__((ext_vector_type(4)));
typedef short    s16x8 __attribute__((ext_vector_type(8)));
typedef short    s16x4 __attribute__((ext_vector_type(4)));
typedef _Float16 h2    __attribute__((ext_vector_type(2)));

static __device__ __forceinline__ short f2bf(float f) {
  uint32_t u = __float_as_uint(f);
  u = (u + 0x7fffu + ((u >> 16) & 1u)) >> 16;  // RNE
  return (short)u;
}

static __device__ __forceinline__ float fdot2(h2 a, h2 b, float c) {
#if __has_builtin(__builtin_amdgcn_fdot2)
  return __builtin_amdgcn_fdot2(a, b, c, false);
#else
  return c + (float)a[0] * (float)b[0] + (float)a[1] * (float)b[1];
#endif
}

template <int IMM>
static __device__ __forceinline__ float swz(float v) {
  return __int_as_float(__builtin_amdgcn_ds_swizzle(__float_as_int(v), IMM));
}

// DPP quad_perm cross-lane (VALU pipe): lane^1, lane^2
static __device__ __forceinline__ float dpp_xor1(float v) {
  return __int_as_float(__builtin_amdgcn_mov_dpp(__float_as_int(v), 0xB1, 0xF, 0xF, true));
}
static __device__ __forceinline__ float dpp_xor2(float v) {
  return __int_as_float(__builtin_amdgcn_mov_dpp(__float_as_int(v), 0x4E, 0xF, 0xF, true));
}

// Raw workgroup barrier WITHOUT the vmcnt(0) drain __syncthreads carries.
static __device__ __forceinline__ void rawbar() {
  __builtin_amdgcn_sched_barrier(0);
  asm volatile("s_waitcnt lgkmcnt(0)" ::: "memory");
  __builtin_amdgcn_s_barrier();
  __builtin_amdgcn_sched_barrier(0);
}

static __device__ __forceinline__ uint32_t pack2(float a, float b) {
  h2 p = { (_Float16)a, (_Float16)b };
  return __builtin_bit_cast(uint32_t, p);
}

static __device__ __forceinline__ h2 bch(uint32_t u) {
  return __builtin_bit_cast(h2, u);
}

// ---------------------------------------------------------------------------
// Grid-wide barrier (persistent kernel). All NWG WGs are co-resident by
// construction (133 KB LDS -> 1 WG/CU, 192 < 256 CUs). Device-scope fences
// per Guideline 16: release (__threadfence: waitcnt + L2 writeback) before
// arrive; acquire (invalidate) after release. Counter is monotonic; host
// zeroes it per launch via hipMemsetAsync.
// ---------------------------------------------------------------------------
static __device__ __forceinline__ void gridbar(uint32_t* bar, uint32_t target) {
  __syncthreads();
  __threadfence();                               // release: drain + writeback
  if (threadIdx.x == 0) {
    __hip_atomic_fetch_add(bar, 1u, __ATOMIC_ACQ_REL, __HIP_MEMORY_SCOPE_AGENT);
    while (__hip_atomic_load(bar, __ATOMIC_ACQUIRE, __HIP_MEMORY_SCOPE_AGENT) < target)
      __builtin_amdgcn_s_sleep(8);
  }
  __syncthreads();
  __threadfence();                               // acquire: invalidate stale
}

// ---------------------------------------------------------------------------
// GEMM role: 512 threads, 256x128 tile, 8 waves as 4Mx2N of 64x64.
// 32 WGs per role cover one 2048-row chunk (rb in [0,32)).
// ---------------------------------------------------------------------------
__device__ void gemm_role(char* smem, int rb,
                          const float* __restrict__ In,
                          const float* __restrict__ W,
                          const float* __restrict__ bi,
                          const float* __restrict__ bh,
                          float* __restrict__ Out) {
  constexpr int LDT = 40;
  short* As = (short*)smem;              // 256 x LDT
  short* Bs = (short*)(smem + 256 * LDT * 2);  // 128 x LDT

  const int tid  = threadIdx.x;
  const int m0   = (rb >> 2) * 256;
  const int n0   = (rb & 3) * 128;
  const int wave = tid >> 6, lane = tid & 63;
  const int wm   = (wave >> 1) * 64;
  const int wn   = (wave & 1) * 64;
  const int quad = lane >> 4, tq = lane & 15;

  f32x4 acc[4][4] = {};

  for (int k0 = 0; k0 < 512; k0 += 32) {
    #pragma unroll
    for (int v = 0; v < 4; ++v) {
      int idx = v * 512 + tid;
      int r = idx >> 3, cc = (idx & 7) * 4;
      f32x4 a = *(const f32x4*)(In + (size_t)(m0 + r) * 512 + k0 + cc);
      s16x4 ap = { f2bf(a.x), f2bf(a.y), f2bf(a.z), f2bf(a.w) };
      *(s16x4*)(&As[r * LDT + cc]) = ap;
    }
    #pragma unroll
    for (int v = 0; v < 2; ++v) {
      int idx = v * 512 + tid;
      int r = idx >> 3, cc = (idx & 7) * 4;
      f32x4 b = *(const f32x4*)(W + (size_t)(n0 + r) * 512 + k0 + cc);
      s16x4 bp = { f2bf(b.x), f2bf(b.y), f2bf(b.z), f2bf(b.w) };
      *(s16x4*)(&Bs[r * LDT + cc]) = bp;
    }
    __syncthreads();

    s16x8 af[4], bfr[4];
    #pragma unroll
    for (int mf = 0; mf < 4; ++mf)
      af[mf] = *(const s16x8*)(&As[(wm + mf * 16 + tq) * LDT + quad * 8]);
    #pragma unroll
    for (int nf = 0; nf < 4; ++nf)
      bfr[nf] = *(const s16x8*)(&Bs[(wn + nf * 16 + tq) * LDT + quad * 8]);
    #pragma unroll
    for (int mf = 0; mf < 4; ++mf)
      #pragma unroll
      for (int nf = 0; nf < 4; ++nf)
        acc[mf][nf] = __builtin_amdgcn_mfma_f32_16x16x32_bf16(
            af[mf], bfr[nf], acc[mf][nf], 0, 0, 0);
    __syncthreads();
  }

  #pragma unroll
  for (int nf = 0; nf < 4; ++nf) {
    int col = n0 + wn + nf * 16 + tq;
    float bv = bi[col] + bh[col];
    #pragma unroll
    for (int mf = 0; mf < 4; ++mf) {
      #pragma unroll
      for (int r = 0; r < 4; ++r) {
        int row = m0 + wm + mf * 16 + quad * 4 + r;
        Out[(size_t)row * 512 + col] = acc[mf][nf][r] + bv;
      }
    }
  }
}

// ---------------------------------------------------------------------------
// R-role weight preamble: executed ONCE per persistent WG (the whole point
// of r8). cols 0..47 -> wreg (unified VGPR/AGPR), cols 48..63 -> wlds.
// ---------------------------------------------------------------------------
static __device__ __forceinline__ void load_weights(char* smem,
                                                    const float* __restrict__ Wh,
                                                    h2 (&wreg)[8][24]) {
  const int tid = threadIdx.x;
  const int c   = tid & 7;
  const int rg  = tid >> 3;
  uint4* wlds = (uint4*)smem;                    // 16*512 entries, 128 KiB
  #pragma unroll
  for (int k = 0; k < 8; ++k) {
    const float* wrow = Wh + (size_t)(rg * 8 + k) * 512 + c * 64;
    #pragma unroll
    for (int u = 0; u < 6; ++u) {
      f32x4 w4 = *(const f32x4*)(wrow + u * 8);
      f32x4 w5 = *(const f32x4*)(wrow + u * 8 + 4);
      wreg[k][u * 4 + 0] = h2{(_Float16)w4.x, (_Float16)w4.y};
      wreg[k][u * 4 + 1] = h2{(_Float16)w4.z, (_Float16)w4.w};
      wreg[k][u * 4 + 2] = h2{(_Float16)w5.x, (_Float16)w5.y};
      wreg[k][u * 4 + 3] = h2{(_Float16)w5.z, (_Float16)w5.w};
    }
    #pragma unroll
    for (int p = 0; p < 2; ++p) {
      f32x4 w4 = *(const f32x4*)(wrow + 48 + p * 8);
      f32x4 w5 = *(const f32x4*)(wrow + 48 + p * 8 + 4);
      uint4 pk;
      pk.x = pack2(w4.x, w4.y);
      pk.y = pack2(w4.z, w4.w);
      pk.z = pack2(w5.x, w5.y);
      pk.w = pack2(w5.z, w5.w);
      wlds[(k * 2 + p) * 512 + tid] = pk;
    }
  }
}

// ---------------------------------------------------------------------------
// One chunk of CS recurrence steps (r4-champion step body, unchanged).
// Thread t = rg*8 + c: rows rg*8..+7, column chunk c*64..+63. xw_y is the
// per-chunk base (local ls indexing). hstate carries h across chunks.
// ---------------------------------------------------------------------------
static __device__ __forceinline__ void run_chunk(char* smem, int b, int chunk,
                                                 h2 (&wreg)[8][24],
                                                 float* __restrict__ xw_y,
                                                 const float* __restrict__ h0l,
                                                 float* __restrict__ hstate) {
  const int tid = threadIdx.x;
  const int c   = tid & 7;
  uint4*    wlds = (uint4*)smem;
  _Float16* hbuf = (_Float16*)(smem + 131072);   // [2][8*72]

  float hini = (chunk == 0) ? h0l[b * 512 + tid] : hstate[b * 512 + tid];
  hbuf[(tid >> 6) * 72 + (tid & 63)] = (_Float16)hini;   // parity 0 (ls=0 even)
  __syncthreads();

#define UBLK(HV, W0)                                                        \
  { h2 p0 = bch((HV).x), p1 = bch((HV).y), p2 = bch((HV).z), p3 = bch((HV).w); \
    _Pragma("unroll")                                                       \
    for (int k = 0; k < 8; ++k) {                                           \
      acc[k] = fdot2(wreg[k][(W0) + 0], p0, acc[k]);                        \
      acc[k] = fdot2(wreg[k][(W0) + 1], p1, acc[k]);                        \
      acc[k] = fdot2(wreg[k][(W0) + 2], p2, acc[k]);                        \
      acc[k] = fdot2(wreg[k][(W0) + 3], p3, acc[k]);                        \
    } }

#define WLDX(g)                                                             \
  { wt0 = wlds[(4 * (g) + 0) * 512 + tid];                                  \
    wt1 = wlds[(4 * (g) + 1) * 512 + tid];                                  \
    wt2 = wlds[(4 * (g) + 2) * 512 + tid];                                  \
    wt3 = wlds[(4 * (g) + 3) * 512 + tid]; }

#define CONSX(K0)                                                           \
  { h2 q0 = bch(q4.x), q1 = bch(q4.y), q2 = bch(q4.z), q3 = bch(q4.w);      \
    h2 r0 = bch(r4.x), r1 = bch(r4.y), r2 = bch(r4.z), r3 = bch(r4.w);      \
    float a = acc[(K0)];                                                    \
    a = fdot2(bch(wt0.x), q0, a); a = fdot2(bch(wt0.y), q1, a);             \
    a = fdot2(bch(wt0.z), q2, a); a = fdot2(bch(wt0.w), q3, a);             \
    a = fdot2(bch(wt1.x), r0, a); a = fdot2(bch(wt1.y), r1, a);             \
    a = fdot2(bch(wt1.z), r2, a); a = fdot2(bch(wt1.w), r3, a);             \
    acc[(K0)] = a;                                                          \
    a = acc[(K0) + 1];                                                      \
    a = fdot2(bch(wt2.x), q0, a); a = fdot2(bch(wt2.y), q1, a);             \
    a = fdot2(bch(wt2.z), q2, a); a = fdot2(bch(wt2.w), q3, a);             \
    a = fdot2(bch(wt3.x), r0, a); a = fdot2(bch(wt3.y), r1, a);             \
    a = fdot2(bch(wt3.z), r2, a); a = fdot2(bch(wt3.w), r3, a);             \
    acc[(K0) + 1] = a; }

  const float* xwp = xw_y + (size_t)b * 512 + tid;
  float xwv = xwp[0];
  float hlast = 0.f;
  for (int ls = 0; ls < CS; ++ls) {
    const int cur = ls & 1, nxt = cur ^ 1;
    int tn = (ls + 1 < CS) ? ls + 1 : ls;
    float xwn = xwp[(size_t)tn * BH];   // prefetch rides across rawbar

    const _Float16* hc = &hbuf[cur * 8 * 72 + c * 72];
#define HLD(i) (*(const uint4*)(hc + (i) * 8))

    float acc[8] = {0, 0, 0, 0, 0, 0, 0, 0};

    uint4 ha = HLD(0), hbv = HLD(1), hx = HLD(2);
    uint4 q4 = HLD(6), r4 = HLD(7);
    uint4 wt0, wt1, wt2, wt3;

    WLDX(0);                         // k=0,1 in flight
    UBLK(ha, 0);   ha  = HLD(3);     // cols  0..7
    CONSX(0);      WLDX(1);          // consume k=0,1; issue k=2,3
    UBLK(hbv, 4);  hbv = HLD(4);     // cols  8..15
    CONSX(2);      WLDX(2);          // consume k=2,3; issue k=4,5
    UBLK(hx, 8);   hx  = HLD(5);     // cols 16..23
    CONSX(4);      WLDX(3);          // consume k=4,5; issue k=6,7
    UBLK(ha, 12);                    // cols 24..31
    CONSX(6);                        // consume k=6,7
    UBLK(hbv, 16);                   // cols 32..39
    UBLK(hx, 20);                    // cols 40..47

    // butterfly: xor1/xor2 on DPP (VALU), xor4 via ds_swizzle
    float r1v[4];
    #pragma unroll
    for (int p = 0; p < 4; ++p) {
      float send = (c & 1) ? acc[2 * p] : acc[2 * p + 1];
      float recv = dpp_xor1(send);
      float keep = (c & 1) ? acc[2 * p + 1] : acc[2 * p];
      r1v[p] = keep + recv;
    }
    float r2v[2];
    #pragma unroll
    for (int p = 0; p < 2; ++p) {
      float send = (c & 2) ? r1v[2 * p] : r1v[2 * p + 1];
      float recv = dpp_xor2(send);
      float keep = (c & 2) ? r1v[2 * p + 1] : r1v[2 * p];
      r2v[p] = keep + recv;
    }
    {
      float send = (c & 4) ? r2v[0] : r2v[1];
      float recv = swz<0x101F>(send);
      float keep = (c & 4) ? r2v[1] : r2v[0];
      float dot  = keep + recv;              // full dot for row == tid

      float pre = dot + xwv;
      float e   = __expf(2.f * pre);         // tanh = 1 - 2/(e^{2x}+1)
      float hni = 1.f - 2.f / (e + 1.f);
      hbuf[nxt * 8 * 72 + (tid >> 6) * 72 + (tid & 63)] = (_Float16)hni;
      xw_y[(size_t)ls * BH + b * 512 + tid] = hni;
      hlast = hni;
    }
    rawbar();                        // lgkm-only barrier; y-store not drained
    xwv = xwn;
#undef HLD
  }
  hstate[b * 512 + tid] = hlast;
#undef UBLK
#undef WLDX
#undef CONSX
}

// ---------------------------------------------------------------------------
// Persistent pipeline kernel. One launch; stage loop inside; grid barrier
// between stages. Roles (by bid):
//   0..63    R1: recur layer-0, chunk s        (xw/y in 4-slot ring in ws)
//   64..127  R2: recur layer-1, chunk s-2      (xw/y in out, full-size)
//   128..159 G1: gemm x@W1^T,  chunk s+1 -> ring
//   160..191 G2: gemm y1@W2^T, chunk s-1: ring -> out
// Ring slot cc&3: written by G1 @ stage cc-1, read by R1 @ cc and G2 @ cc+1,
// next write @ cc+3 -> safe. Weights loaded ONCE (the r7-measured 61 us/launch
// preamble was the dominant cost).
// ---------------------------------------------------------------------------
__global__ __launch_bounds__(512, 1)
void rnn_all(const float* __restrict__ x, const float* __restrict__ h0,
             const float* __restrict__ Wih, const float* __restrict__ Whh,
             const float* __restrict__ bih, const float* __restrict__ bhh,
             float* __restrict__ ws, float* __restrict__ out) {
  __shared__ __align__(16) char smem[133376];  // 128K wlds + 2.25K hbuf
  const int bid = blockIdx.x;
  float* hn = out + (size_t)TBH;
  uint32_t* bar = (uint32_t*)((char*)ws + BAR_BYTE_OFF);

  if (bid < 128) {                    // R roles
    const int b     = bid & 63;
    const int layer = bid >> 6;       // 0 = R1, 1 = R2
    const int delay = layer * 2;      // R1: cc = s; R2: cc = s-2
    const float* Wh  = Whh + (size_t)layer * H_ * H_;
    const float* h0l = h0  + (size_t)layer * BH;
    float* hstate    = hn  + (size_t)layer * BH;

    h2 wreg[8][24];
    load_weights(smem, Wh, wreg);     // ONCE

    for (int it = 0; it < NSTAGE; ++it) {
      int cc = (it - 1) - delay;
      if (cc >= 0 && cc < NC) {
        float* xw_y = (layer == 0) ? ws + (size_t)(cc & 3) * CSZ
                                   : out + (size_t)cc * CSZ;
        run_chunk(smem, b, cc, wreg, xw_y, h0l, hstate);
      }
      gridbar(bar, (uint32_t)(it + 1) * NWG);
    }
  } else {                            // G roles
    const int g2 = (bid >= 160) ? 1 : 0;
    const int rb = bid - (g2 ? 160 : 128);
    const float* Wg  = Wih + (size_t)g2 * H_ * H_;
    const float* big = bih + (size_t)g2 * H_;
    const float* bhg = bhh + (size_t)g2 * H_;

    for (int it = 0; it < NSTAGE; ++it) {
      int s  = it - 1;
      int cc = g2 ? (s - 1) : (s + 1);
      if (cc >= 0 && cc < NC) {
        const float* In = g2 ? ws + (size_t)(cc & 3) * CSZ
                             : x + (size_t)cc * CSZ;
        float* Out      = g2 ? out + (size_t)cc * CSZ
                             : ws + (size_t)(cc & 3) * CSZ;
        gemm_role(smem, rb, In, Wg, big, bhg, Out);
      }
      gridbar(bar, (uint32_t)(it + 1) * NWG);
    }
  }
}

// ---------------------------------------------------------------------------
extern "C" void kernel_launch(void* const* d_in, const int* in_sizes, int n_in,
                              void* d_out, int out_size, void* d_ws, size_t ws_size,
                              hipStream_t stream) {
  const float* x   = (const float*)d_in[0];
  const float* h0  = (const float*)d_in[1];
  const float* Wih = (const float*)d_in[2];
  const float* Whh = (const float*)d_in[3];
  const float* bih = (const float*)d_in[4];
  const float* bhh = (const float*)d_in[5];
  float* out = (float*)d_out;
  float* ws  = (float*)d_ws;    // 16 MiB xw/y ring + barrier word @ +16 MiB

  hipMemsetAsync((char*)d_ws + BAR_BYTE_OFF, 0, 256, stream);
  rnn_all<<<NWG, 512, 0, stream>>>(x, h0, Wih, Whh, bih, bhh, ws, out);
}

// Round 9
// 1248.157 us; speedup vs baseline: 1.7049x; 1.7049x over previous
//
#include <hip/hip_runtime.h>
#include <stdint.h>

#define T_ 512
#define B_ 64
#define H_ 512
#define L_ 2
#define TBH (T_*B_*H_)   // 16777216
#define BH  (B_*H_)      // 32768
#define NC  8            // time chunks (champion config)
#define CS  64           // steps per chunk
#define CROWS (CS*B_)    // 4096 rows per chunk
#define CSZ ((size_t)CROWS*H_)       // floats per chunk slot (8 MiB)
#define WPK_OFF ((size_t)4*CSZ)      // ws float-offset of fp16 weight pack (32 MiB)
#define WPK_U4L (64*512)             // uint4 per layer of packed weights (512 KiB)

typedef float    f32x4 __attribute__((ext_vector_type(4)));
typedef short    s16x8 __attribute__((ext_vector_type(8)));
typedef short    s16x4 __attribute__((ext_vector_type(4)));
typedef _Float16 h2    __attribute__((ext_vector_type(2)));

static __device__ __forceinline__ short f2bf(float f) {
  uint32_t u = __float_as_uint(f);
  u = (u + 0x7fffu + ((u >> 16) & 1u)) >> 16;  // RNE
  return (short)u;
}

static __device__ __forceinline__ float fdot2(h2 a, h2 b, float c) {
#if __has_builtin(__builtin_amdgcn_fdot2)
  return __builtin_amdgcn_fdot2(a, b, c, false);
#else
  return c + (float)a[0] * (float)b[0] + (float)a[1] * (float)b[1];
#endif
}

template <int IMM>
static __device__ __forceinline__ float swz(float v) {
  return __int_as_float(__builtin_amdgcn_ds_swizzle(__float_as_int(v), IMM));
}

// DPP quad_perm cross-lane (VALU pipe): lane^1, lane^2
static __device__ __forceinline__ float dpp_xor1(float v) {
  return __int_as_float(__builtin_amdgcn_mov_dpp(__float_as_int(v), 0xB1, 0xF, 0xF, true));
}
static __device__ __forceinline__ float dpp_xor2(float v) {
  return __int_as_float(__builtin_amdgcn_mov_dpp(__float_as_int(v), 0x4E, 0xF, 0xF, true));
}

// Raw workgroup barrier WITHOUT the vmcnt(0) drain __syncthreads carries.
static __device__ __forceinline__ void rawbar() {
  __builtin_amdgcn_sched_barrier(0);
  asm volatile("s_waitcnt lgkmcnt(0)" ::: "memory");
  __builtin_amdgcn_s_barrier();
  __builtin_amdgcn_sched_barrier(0);
}

static __device__ __forceinline__ uint32_t pack2(float a, float b) {
  h2 p = { (_Float16)a, (_Float16)b };
  return __builtin_bit_cast(uint32_t, p);
}

static __device__ __forceinline__ h2 bch(uint32_t u) {
  return __builtin_bit_cast(h2, u);
}

// ---------------------------------------------------------------------------
// One-time pre-pack of Whh (both layers) to fp16 in CONSUMPTION ORDER,
// layout [64][512] uint4 per layer: wave-op j reads pack[j][tid] ->
// lane-contiguous 16B = perfectly coalesced 1 KB/op. j = k*6+u (wreg part,
// 48 ops) then 48 + k*2+p (wlds part, 16 ops). Same (_Float16) casts as the
// old in-preamble conversion -> bit-identical step arithmetic.
// ---------------------------------------------------------------------------
__global__ __launch_bounds__(512, 1)
void prepack(const float* __restrict__ Whh, float* __restrict__ ws) {
  const int l = blockIdx.x;       // 2 blocks = 2 layers
  const int tid = threadIdx.x;
  const int c = tid & 7, rg = tid >> 3;
  uint4* dst = (uint4*)(ws + WPK_OFF) + (size_t)l * WPK_U4L;
  const float* W = Whh + (size_t)l * H_ * H_;
  #pragma unroll
  for (int k = 0; k < 8; ++k) {
    const float* wrow = W + (size_t)(rg * 8 + k) * H_ + c * 64;
    #pragma unroll
    for (int u = 0; u < 6; ++u) {
      f32x4 w4 = *(const f32x4*)(wrow + u * 8);
      f32x4 w5 = *(const f32x4*)(wrow + u * 8 + 4);
      uint4 pk;
      pk.x = pack2(w4.x, w4.y);
      pk.y = pack2(w4.z, w4.w);
      pk.z = pack2(w5.x, w5.y);
      pk.w = pack2(w5.z, w5.w);
      dst[(k * 6 + u) * 512 + tid] = pk;
    }
    #pragma unroll
    for (int p = 0; p < 2; ++p) {
      f32x4 w4 = *(const f32x4*)(wrow + 48 + p * 8);
      f32x4 w5 = *(const f32x4*)(wrow + 48 + p * 8 + 4);
      uint4 pk;
      pk.x = pack2(w4.x, w4.y);
      pk.y = pack2(w4.z, w4.w);
      pk.z = pack2(w5.x, w5.y);
      pk.w = pack2(w5.z, w5.w);
      dst[(48 + k * 2 + p) * 512 + tid] = pk;
    }
  }
}

// ---------------------------------------------------------------------------
// GEMM role (unchanged): 512 threads, 256x128 tile, 8 waves as 4Mx2N of 64x64.
// ---------------------------------------------------------------------------
__device__ void gemm_role(char* smem, int rb,
                          const float* __restrict__ In,
                          const float* __restrict__ W,
                          const float* __restrict__ bi,
                          const float* __restrict__ bh,
                          float* __restrict__ Out) {
  constexpr int LDT = 40;
  short* As = (short*)smem;              // 256 x LDT
  short* Bs = (short*)(smem + 256 * LDT * 2);  // 128 x LDT

  const int tid  = threadIdx.x;
  const int m0   = (rb >> 2) * 256;
  const int n0   = (rb & 3) * 128;
  const int wave = tid >> 6, lane = tid & 63;
  const int wm   = (wave >> 1) * 64;
  const int wn   = (wave & 1) * 64;
  const int quad = lane >> 4, tq = lane & 15;

  f32x4 acc[4][4] = {};

  for (int k0 = 0; k0 < 512; k0 += 32) {
    #pragma unroll
    for (int v = 0; v < 4; ++v) {
      int idx = v * 512 + tid;
      int r = idx >> 3, cc = (idx & 7) * 4;
      f32x4 a = *(const f32x4*)(In + (size_t)(m0 + r) * 512 + k0 + cc);
      s16x4 ap = { f2bf(a.x), f2bf(a.y), f2bf(a.z), f2bf(a.w) };
      *(s16x4*)(&As[r * LDT + cc]) = ap;
    }
    #pragma unroll
    for (int v = 0; v < 2; ++v) {
      int idx = v * 512 + tid;
      int r = idx >> 3, cc = (idx & 7) * 4;
      f32x4 b = *(const f32x4*)(W + (size_t)(n0 + r) * 512 + k0 + cc);
      s16x4 bp = { f2bf(b.x), f2bf(b.y), f2bf(b.z), f2bf(b.w) };
      *(s16x4*)(&Bs[r * LDT + cc]) = bp;
    }
    __syncthreads();

    s16x8 af[4], bfr[4];
    #pragma unroll
    for (int mf = 0; mf < 4; ++mf)
      af[mf] = *(const s16x8*)(&As[(wm + mf * 16 + tq) * LDT + quad * 8]);
    #pragma unroll
    for (int nf = 0; nf < 4; ++nf)
      bfr[nf] = *(const s16x8*)(&Bs[(wn + nf * 16 + tq) * LDT + quad * 8]);
    #pragma unroll
    for (int mf = 0; mf < 4; ++mf)
      #pragma unroll
      for (int nf = 0; nf < 4; ++nf)
        acc[mf][nf] = __builtin_amdgcn_mfma_f32_16x16x32_bf16(
            af[mf], bfr[nf], acc[mf][nf], 0, 0, 0);
    __syncthreads();
  }

  #pragma unroll
  for (int nf = 0; nf < 4; ++nf) {
    int col = n0 + wn + nf * 16 + tq;
    float bv = bi[col] + bh[col];
    #pragma unroll
    for (int mf = 0; mf < 4; ++mf) {
      #pragma unroll
      for (int r = 0; r < 4; ++r) {
        int row = m0 + wm + mf * 16 + quad * 4 + r;
        Out[(size_t)row * 512 + col] = acc[mf][nf][r] + bv;
      }
    }
  }
}

// ---------------------------------------------------------------------------
// Recurrence role (one chunk of CS steps). 1 WG = 1 batch, 512 threads.
// Thread t = rg*8 + c: rows rg*8..+7, column chunk c*64..+63.
// r9: the weight preamble reads the COALESCED fp16 pack (64 uint4/thread,
// wave-op j = lane-contiguous 1 KB) instead of 128 strided f32x4 loads +
// ~500 cvt ops -- attacks the measured ~61 us per-launch preamble.
// Step body = r4 champion, byte-identical.
// ---------------------------------------------------------------------------
__device__ void recur_role(char* smem, int b, int chunk,
                           float* __restrict__ xw_y,
                           const float* __restrict__ h0l,
                           const uint4* __restrict__ wpk,
                           float* __restrict__ hstate) {
  const int tid = threadIdx.x;
  const int c   = tid & 7;

  uint4*    wlds = (uint4*)smem;                     // 16*512 entries, 128 KiB
  _Float16* hbuf = (_Float16*)(smem + 131072);       // [2][8*72]

  const uint4* wp = wpk + tid;
  h2 wreg[8][24];
  #pragma unroll
  for (int k = 0; k < 8; ++k)
    #pragma unroll
    for (int u = 0; u < 6; ++u) {
      uint4 v = wp[(k * 6 + u) * 512];
      wreg[k][u * 4 + 0] = bch(v.x);
      wreg[k][u * 4 + 1] = bch(v.y);
      wreg[k][u * 4 + 2] = bch(v.z);
      wreg[k][u * 4 + 3] = bch(v.w);
    }
  #pragma unroll
  for (int j = 0; j < 16; ++j)
    wlds[j * 512 + tid] = wp[(48 + j) * 512];

  float hini = (chunk == 0) ? h0l[b * 512 + tid] : hstate[b * 512 + tid];
  hbuf[(tid >> 6) * 72 + (tid & 63)] = (_Float16)hini;   // parity 0 (ls=0 even)
  __syncthreads();

#define UBLK(HV, W0)                                                        \
  { h2 p0 = bch((HV).x), p1 = bch((HV).y), p2 = bch((HV).z), p3 = bch((HV).w); \
    _Pragma("unroll")                                                       \
    for (int k = 0; k < 8; ++k) {                                           \
      acc[k] = fdot2(wreg[k][(W0) + 0], p0, acc[k]);                        \
      acc[k] = fdot2(wreg[k][(W0) + 1], p1, acc[k]);                        \
      acc[k] = fdot2(wreg[k][(W0) + 2], p2, acc[k]);                        \
      acc[k] = fdot2(wreg[k][(W0) + 3], p3, acc[k]);                        \
    } }

#define WLDX(g)                                                             \
  { wt0 = wlds[(4 * (g) + 0) * 512 + tid];                                  \
    wt1 = wlds[(4 * (g) + 1) * 512 + tid];                                  \
    wt2 = wlds[(4 * (g) + 2) * 512 + tid];                                  \
    wt3 = wlds[(4 * (g) + 3) * 512 + tid]; }

#define CONSX(K0)                                                           \
  { h2 q0 = bch(q4.x), q1 = bch(q4.y), q2 = bch(q4.z), q3 = bch(q4.w);      \
    h2 r0 = bch(r4.x), r1 = bch(r4.y), r2 = bch(r4.z), r3 = bch(r4.w);      \
    float a = acc[(K0)];                                                    \
    a = fdot2(bch(wt0.x), q0, a); a = fdot2(bch(wt0.y), q1, a);             \
    a = fdot2(bch(wt0.z), q2, a); a = fdot2(bch(wt0.w), q3, a);             \
    a = fdot2(bch(wt1.x), r0, a); a = fdot2(bch(wt1.y), r1, a);             \
    a = fdot2(bch(wt1.z), r2, a); a = fdot2(bch(wt1.w), r3, a);             \
    acc[(K0)] = a;                                                          \
    a = acc[(K0) + 1];                                                      \
    a = fdot2(bch(wt2.x), q0, a); a = fdot2(bch(wt2.y), q1, a);             \
    a = fdot2(bch(wt2.z), q2, a); a = fdot2(bch(wt2.w), q3, a);             \
    a = fdot2(bch(wt3.x), r0, a); a = fdot2(bch(wt3.y), r1, a);             \
    a = fdot2(bch(wt3.z), r2, a); a = fdot2(bch(wt3.w), r3, a);             \
    acc[(K0) + 1] = a; }

  const float* xwp = xw_y + (size_t)b * 512 + tid;
  float xwv = xwp[0];
  float hlast = 0.f;
  for (int ls = 0; ls < CS; ++ls) {
    const int cur = ls & 1, nxt = cur ^ 1;
    int tn = (ls + 1 < CS) ? ls + 1 : ls;
    float xwn = xwp[(size_t)tn * BH];   // prefetch rides across rawbar

    const _Float16* hc = &hbuf[cur * 8 * 72 + c * 72];
#define HLD(i) (*(const uint4*)(hc + (i) * 8))

    float acc[8] = {0, 0, 0, 0, 0, 0, 0, 0};

    uint4 ha = HLD(0), hbv = HLD(1), hx = HLD(2);
    uint4 q4 = HLD(6), r4 = HLD(7);
    uint4 wt0, wt1, wt2, wt3;

    WLDX(0);                         // k=0,1 in flight
    UBLK(ha, 0);   ha  = HLD(3);     // cols  0..7
    CONSX(0);      WLDX(1);          // consume k=0,1; issue k=2,3
    UBLK(hbv, 4);  hbv = HLD(4);     // cols  8..15
    CONSX(2);      WLDX(2);          // consume k=2,3; issue k=4,5
    UBLK(hx, 8);   hx  = HLD(5);     // cols 16..23
    CONSX(4);      WLDX(3);          // consume k=4,5; issue k=6,7
    UBLK(ha, 12);                    // cols 24..31
    CONSX(6);                        // consume k=6,7
    UBLK(hbv, 16);                   // cols 32..39
    UBLK(hx, 20);                    // cols 40..47

    // butterfly: xor1/xor2 on DPP (VALU), xor4 via ds_swizzle
    float r1v[4];
    #pragma unroll
    for (int p = 0; p < 4; ++p) {
      float send = (c & 1) ? acc[2 * p] : acc[2 * p + 1];
      float recv = dpp_xor1(send);
      float keep = (c & 1) ? acc[2 * p + 1] : acc[2 * p];
      r1v[p] = keep + recv;
    }
    float r2v[2];
    #pragma unroll
    for (int p = 0; p < 2; ++p) {
      float send = (c & 2) ? r1v[2 * p] : r1v[2 * p + 1];
      float recv = dpp_xor2(send);
      float keep = (c & 2) ? r1v[2 * p + 1] : r1v[2 * p];
      r2v[p] = keep + recv;
    }
    {
      float send = (c & 4) ? r2v[0] : r2v[1];
      float recv = swz<0x101F>(send);
      float keep = (c & 4) ? r2v[1] : r2v[0];
      float dot  = keep + recv;              // full dot for row == tid

      float pre = dot + xwv;
      float e   = __expf(2.f * pre);         // tanh = 1 - 2/(e^{2x}+1)
      float hni = 1.f - 2.f / (e + 1.f);
      hbuf[nxt * 8 * 72 + (tid >> 6) * 72 + (tid & 63)] = (_Float16)hni;
      xw_y[(size_t)ls * BH + b * 512 + tid] = hni;
      hlast = hni;
    }
    rawbar();                        // lgkm-only barrier; y-store not drained
    xwv = xwn;
#undef HLD
  }
  hstate[b * 512 + tid] = hlast;   // final chunk leaves h_n in place
#undef UBLK
#undef WLDX
#undef CONSX
}

// ---------------------------------------------------------------------------
// Pipeline stage s (depth-3 software pipeline over 8 time-chunks):
//   blocks   0..63  R1: recur layer-0, chunk s        (0 <= s <= 7)
//   blocks  64..127 R2: recur layer-1, chunk s-2      (2 <= s <= 9)
//   blocks 128..191 G1: gemm x@W1^T,  chunk s+1       (-1 <= s <= 6)
//   blocks 192..255 G2: gemm y1@W2^T, chunk s-1       (1 <= s <= 8)
// xw1/y1 in a 4-slot ring in ws (slots s+1, s, s-1 distinct mod 4 --
// validated r1/r6); fp16 weight pack at ws+32MiB. h-states in hn slots.
// ---------------------------------------------------------------------------
__global__ __launch_bounds__(512, 1)
void stage(int s,
           const float* __restrict__ x, const float* __restrict__ h0,
           const float* __restrict__ Wih, const float* __restrict__ Whh,
           const float* __restrict__ bih, const float* __restrict__ bhh,
           float* __restrict__ ws, float* __restrict__ out) {
  __shared__ __align__(16) char smem[133376];  // 128K wlds + 2.25K hbuf
  const int role = blockIdx.x >> 6;
  const int rb   = blockIdx.x & 63;
  float* hn = out + (size_t)TBH;
  const uint4* wpk = (const uint4*)(ws + WPK_OFF);

  if (role == 0) {                    // R1
    int cc = s;
    if (cc < 0 || cc >= NC) return;
    recur_role(smem, rb, cc, ws + (size_t)(cc & 3) * CSZ, h0, wpk, hn);
  } else if (role == 1) {             // R2
    int cc = s - 2;
    if (cc < 0 || cc >= NC) return;
    recur_role(smem, rb, cc, out + (size_t)cc * CSZ, h0 + BH,
               wpk + WPK_U4L, hn + BH);
  } else if (role == 2) {             // G1
    int cc = s + 1;
    if (cc < 0 || cc >= NC) return;
    gemm_role(smem, rb, x + (size_t)cc * CSZ, Wih, bih, bhh,
              ws + (size_t)(cc & 3) * CSZ);
  } else {                            // G2
    int cc = s - 1;
    if (cc < 0 || cc >= NC) return;
    gemm_role(smem, rb, ws + (size_t)(cc & 3) * CSZ,
              Wih + (size_t)H_ * H_, bih + H_, bhh + H_,
              out + (size_t)cc * CSZ);
  }
}

// ---------------------------------------------------------------------------
extern "C" void kernel_launch(void* const* d_in, const int* in_sizes, int n_in,
                              void* d_out, int out_size, void* d_ws, size_t ws_size,
                              hipStream_t stream) {
  const float* x   = (const float*)d_in[0];
  const float* h0  = (const float*)d_in[1];
  const float* Wih = (const float*)d_in[2];
  const float* Whh = (const float*)d_in[3];
  const float* bih = (const float*)d_in[4];
  const float* bhh = (const float*)d_in[5];
  float* out = (float*)d_out;
  float* ws  = (float*)d_ws;    // 32 MiB xw/y ring + 1 MiB fp16 weight pack

  prepack<<<2, 512, 0, stream>>>(Whh, ws);
  for (int s = -1; s <= NC + 1; ++s)
    stage<<<256, 512, 0, stream>>>(s, x, h0, Wih, Whh, bih, bhh, ws, out);
}